// Round 15
// baseline (339.291 us; speedup 1.0000x reference)
//
#include <hip/hip_runtime.h>
#include <math.h>

#define N_NODES 100000
#define N_EDGES 400000
#define NG 2048
#define H 128
#define NV 100
#define NLAYERS 3
#define SLOPE 0.2f

// scal layout (256 floats = 1 KB, all zeroed). Cross-XCD rule (R11 lesson):
// never mix atomic and plain stores on one 128B line within a dispatch.
//  [0]       ea_sum        (atomic, k_prep)
//  [32..34]  dot_l         (atomic, k_prep)
//  [48]      alloc counter (atomic, k_alloc)
//  [64..127] deg hist      (atomic, k_alloc)
//  [128..191] binbase      (plain store in k_scatter blk1954; read by k_perm)
//  [192..255] bincur       (atomic, k_perm)
#define SCAL_N 256

typedef __attribute__((ext_vector_type(8))) short bf16x8;
typedef __attribute__((ext_vector_type(4))) float f32x4;

__device__ __forceinline__ float wave_reduce_sum(float v){
  #pragma unroll
  for (int off = 32; off > 0; off >>= 1) v += __shfl_xor(v, off, 64);
  return v;
}
__device__ __forceinline__ unsigned short rne_bf16(float f){
  unsigned int u = __float_as_uint(f);
  u += 0x7FFF + ((u >> 16) & 1);
  return (unsigned short)(u >> 16);
}

// ---- fused prep: convW | convE | out_init | dots | ea_sum | deg -------------
#define PB_CONVW 320                    // 5*16384/256 (single RNE plane now)
#define PB_CONVE (PB_CONVW + 50)        // NV*H/256
#define PB_OUT   (PB_CONVE + 8)         // NG/256
#define PB_DOTS  (PB_OUT + 1)           // 3 waves in one block
#define PB_EASUM (PB_DOTS + 256)
#define PB_DEG   (PB_EASUM + 1954)      // (E+N)/256
__global__ __launch_bounds__(256) void k_prep(
    const float* __restrict__ gat_W, const float* __restrict__ lin_W,
    unsigned short* __restrict__ Wf,
    const float* __restrict__ emb, unsigned short* __restrict__ embb,
    const float* __restrict__ ea, const float* __restrict__ ew,
    const float* __restrict__ ae, float* __restrict__ scal,
    const float* __restrict__ wp_b, float* __restrict__ out,
    const int* __restrict__ ei, int* __restrict__ deg)
{
  int b = blockIdx.x, tid = threadIdx.x;
  if (b < PB_CONVW){
    // W -> RNE bf16, MFMA B-fragment order:
    // idx = m*16384 + k0i*4096 + ct*512 + lane*8 + j
    // k = k0i*32 + (lane>>4)*8 + j, n = ct*16 + (lane&15)
    int i = b*256 + tid;
    int m   = i >> 14;
    int r   = i & 16383;
    int k0i = r >> 12;
    int r3  = r & 4095;
    int ct  = r3 >> 9;
    int r4  = r3 & 511;
    int lane= r4 >> 3;
    int j   = r4 & 7;
    int q = lane >> 4, ln = lane & 15;
    int k = k0i*32 + q*8 + j;
    int n = ct*16 + ln;
    const float* src = (m < 3) ? (gat_W + m*16384) : (lin_W + (m-3)*16384);
    Wf[i] = rne_bf16(src[k*H + n]);
  } else if (b < PB_CONVE){
    int i = (b - PB_CONVW)*256 + tid;
    if (i < NV*H) embb[i] = rne_bf16(emb[i]);
  } else if (b < PB_OUT){
    int g = (b - PB_CONVE)*256 + tid;
    if (g < NG) out[g] = wp_b[0];
  } else if (b < PB_DOTS){
    int l = tid >> 6, ln = tid & 63;
    if (l < NLAYERS){
      float p = ew[l*H + ln]*ae[l*H + ln] + ew[l*H + ln + 64]*ae[l*H + ln + 64];
      p = wave_reduce_sum(p);
      if (ln == 0) atomicAdd(&scal[32 + l], p);
    }
  } else if (b < PB_EASUM){
    int i = (b - PB_DOTS)*256 + tid;
    int stride = 256*256;
    float v = 0.f;
    for (; i < N_EDGES; i += stride) v += ea[i];
    v = wave_reduce_sum(v);
    if ((tid & 63) == 0) atomicAdd(&scal[0], v);
  } else {
    int i = (b - PB_EASUM)*256 + tid;
    if (i < N_EDGES + N_NODES){
      int d = (i < N_EDGES) ? ei[N_EDGES + i] : (i - N_EDGES);
      atomicAdd(&deg[d], 1);
    }
  }
}

// CSR range alloc (block scan + 1 atomic) + degree histogram (LDS-aggregated)
__global__ __launch_bounds__(256) void k_alloc(
    const int* __restrict__ deg, int* __restrict__ row_ptr,
    int* __restrict__ counter, int* __restrict__ hist){
  __shared__ int wsum[4];
  __shared__ int base;
  __shared__ int lhist[64];
  if (threadIdx.x < 64) lhist[threadIdx.x] = 0;
  int n = blockIdx.x * 256 + threadIdx.x;
  int d = (n < N_NODES) ? deg[n] : 0;
  int lane = threadIdx.x & 63, wid = threadIdx.x >> 6;
  int v = d;
  #pragma unroll
  for (int off = 1; off < 64; off <<= 1){
    int u = __shfl_up(v, off, 64);
    if (lane >= off) v += u;
  }
  if (lane == 63) wsum[wid] = v;
  __syncthreads();
  if (threadIdx.x == 0){
    int t0 = wsum[0], t1 = wsum[1], t2 = wsum[2], t3 = wsum[3];
    base = atomicAdd(counter, t0 + t1 + t2 + t3);
    wsum[0] = 0; wsum[1] = t0; wsum[2] = t0 + t1; wsum[3] = t0 + t1 + t2;
  }
  if (n < N_NODES) atomicAdd(&lhist[min(d, 63)], 1);
  __syncthreads();
  if (n < N_NODES) row_ptr[n] = base + wsum[wid] + (v - d);
  if (threadIdx.x < 64 && lhist[threadIdx.x] > 0)
    atomicAdd(&hist[threadIdx.x], lhist[threadIdx.x]);
}

// edge scatter; extra block 1954 = 64-bin exclusive scan (hist -> binbase)
__global__ void k_scatter(const int* __restrict__ ei, const float* __restrict__ ea,
                          const float* __restrict__ scal, const int* __restrict__ row_ptr,
                          int* __restrict__ cursor, int* __restrict__ csr_src,
                          float* __restrict__ csr_ea,
                          const int* __restrict__ hist, int* __restrict__ binbase){
  if (blockIdx.x == 1954){
    int lane = threadIdx.x;
    if (lane < 64){
      int v = hist[lane];
      #pragma unroll
      for (int off = 1; off < 64; off <<= 1){
        int u = __shfl_up(v, off, 64);
        if (lane >= off) v += u;
      }
      binbase[lane] = v - hist[lane];   // exclusive
    }
    return;
  }
  int i = blockIdx.x * blockDim.x + threadIdx.x;
  if (i >= N_EDGES + N_NODES) return;
  int s, d; float v;
  if (i < N_EDGES){ s = ei[i]; d = ei[N_EDGES + i]; v = ea[i]; }
  else            { s = d = i - N_EDGES; v = scal[0] * (1.0f / N_EDGES); }  // ea_mean
  int pos = row_ptr[d] + atomicAdd(&cursor[d], 1);
  csr_src[pos] = s;
  csr_ea[pos]  = v;
}

// degree-sorted permutation (block-aggregated bin atomics)
__global__ __launch_bounds__(256) void k_perm(
    const int* __restrict__ deg, const int* __restrict__ binbase,
    int* __restrict__ bincur, int* __restrict__ perm){
  __shared__ int lhist[64];
  __shared__ int lbase[64];
  if (threadIdx.x < 64) lhist[threadIdx.x] = 0;
  __syncthreads();
  int n = blockIdx.x * 256 + threadIdx.x;
  int d = 0, rank = 0;
  if (n < N_NODES){
    d = min(deg[n], 63);
    rank = atomicAdd(&lhist[d], 1);
  }
  __syncthreads();
  if (threadIdx.x < 64){
    int c = lhist[threadIdx.x];
    lbase[threadIdx.x] = (c > 0) ? atomicAdd(&bincur[threadIdx.x], c) : 0;
  }
  __syncthreads();
  if (n < N_NODES) perm[binbase[d] + lbase[d] + rank] = n;
}

// ---- MFMA GEMM: bf16 A, RNE-bf16 W (single term), 32KB W in LDS -------------
// Block = 256 thr = 4 waves; block tile 128 rows; wave tile 32 rows (2 m-tiles);
// 4 blocks/CU. mode 0: Cb=bf16(acc), a_s/a_d epilogue; mode 1: relu+bias;
// mode 2: relu(acc+bias)·att1 -> atomicAdd out[batch[row]]
__global__ __launch_bounds__(256, 4) void k_gemm(
    const unsigned short* __restrict__ Ab, const int* __restrict__ xmap,
    const unsigned short* __restrict__ Wf,      // fragment-ordered, 16384 ushorts
    unsigned short* __restrict__ Cb,
    const float* __restrict__ att1, const float* __restrict__ att2,
    float* __restrict__ a_s_out, float* __restrict__ a_d_out,
    const float* __restrict__ bias,
    const int* __restrict__ batch, float* __restrict__ out,
    int mode)
{
  __shared__ unsigned short lw[16384];   // 32 KB single plane
  int tid  = threadIdx.x;
  int w    = tid >> 6;
  int lane = tid & 63;
  int q    = lane >> 4;
  int ln   = lane & 15;
  int waveRow = blockIdx.x*128 + w*32;

  bf16x8 af[2][4];
  #pragma unroll
  for (int m = 0; m < 2; ++m){
    int r = waveRow + m*16 + ln;
    if (r >= N_NODES) r = N_NODES - 1;
    if (xmap) r = xmap[r];
    const unsigned short* Ar = Ab + (size_t)r*H;
    #pragma unroll
    for (int k0i = 0; k0i < 4; ++k0i)
      af[m][k0i] = *(const bf16x8*)(Ar + k0i*32 + q*8);
  }

  // stage W (32 KB, 16B/thread x 8)
  #pragma unroll
  for (int i = 0; i < 8; ++i){
    int idx = (i*256 + tid) * 8;
    *(bf16x8*)(lw + idx) = *(const bf16x8*)(Wf + idx);
  }
  __syncthreads();

  f32x4 acc[2][8];
  #pragma unroll
  for (int m = 0; m < 2; ++m)
    #pragma unroll
    for (int ct = 0; ct < 8; ++ct) acc[m][ct] = (f32x4){0.f,0.f,0.f,0.f};

  #pragma unroll
  for (int k0i = 0; k0i < 4; ++k0i){
    #pragma unroll
    for (int ct = 0; ct < 8; ++ct){
      bf16x8 bw = *(const bf16x8*)(lw + k0i*4096 + ct*512 + lane*8);
      #pragma unroll
      for (int m = 0; m < 2; ++m)
        acc[m][ct] = __builtin_amdgcn_mfma_f32_16x16x32_bf16(af[m][k0i], bw, acc[m][ct], 0,0,0);
    }
  }

  // C/D layout: col = ct*16 + ln, row = (m-tile base) + q*4 + r
  if (mode == 0){
    float as_l[8], ad_l[8];
    #pragma unroll
    for (int ct = 0; ct < 8; ++ct){ as_l[ct] = att1[ct*16+ln]; ad_l[ct] = att2[ct*16+ln]; }
    #pragma unroll
    for (int m = 0; m < 2; ++m){
      #pragma unroll
      for (int r = 0; r < 4; ++r){
        int grow = waveRow + m*16 + q*4 + r;
        bool ok = grow < N_NODES;
        float ps = 0.f, pd = 0.f;
        #pragma unroll
        for (int ct = 0; ct < 8; ++ct){
          float v = acc[m][ct][r];
          if (ok) Cb[(size_t)grow*H + ct*16 + ln] = rne_bf16(v);
          ps += v * as_l[ct]; pd += v * ad_l[ct];
        }
        #pragma unroll
        for (int mk = 8; mk > 0; mk >>= 1){
          ps += __shfl_xor(ps, mk, 64);
          pd += __shfl_xor(pd, mk, 64);
        }
        if (ok && ln == 0){ a_s_out[grow] = ps; a_d_out[grow] = pd; }
      }
    }
  } else if (mode == 1){
    float b_l[8];
    #pragma unroll
    for (int ct = 0; ct < 8; ++ct) b_l[ct] = bias[ct*16+ln];
    #pragma unroll
    for (int m = 0; m < 2; ++m){
      #pragma unroll
      for (int r = 0; r < 4; ++r){
        int grow = waveRow + m*16 + q*4 + r;
        if (grow >= N_NODES) continue;
        #pragma unroll
        for (int ct = 0; ct < 8; ++ct)
          Cb[(size_t)grow*H + ct*16 + ln] = rne_bf16(fmaxf(acc[m][ct][r] + b_l[ct], 0.f));
      }
    }
  } else {
    float b_l[8], wp_l[8];
    #pragma unroll
    for (int ct = 0; ct < 8; ++ct){ b_l[ct] = bias[ct*16+ln]; wp_l[ct] = att1[ct*16+ln]; }
    #pragma unroll
    for (int m = 0; m < 2; ++m){
      #pragma unroll
      for (int r = 0; r < 4; ++r){
        int grow = waveRow + m*16 + q*4 + r;
        bool ok = grow < N_NODES;
        float ps = 0.f;
        #pragma unroll
        for (int ct = 0; ct < 8; ++ct)
          ps += fmaxf(acc[m][ct][r] + b_l[ct], 0.f) * wp_l[ct];
        #pragma unroll
        for (int mk = 8; mk > 0; mk >>= 1) ps += __shfl_xor(ps, mk, 64);
        if (ok && ln == 0) atomicAdd(&out[batch[grow]], ps);
      }
    }
  }
}

// ---- aggregate: 2 nodes/wave via degree-sorted perm, 4 cols/lane ------------
// Equal-degree pairing (perm) kills maxd divergence + block-duration tail.
__global__ __launch_bounds__(256, 4) void k_aggregate(
    const uint2* __restrict__ xtb2, const float* __restrict__ a_s,
    const float* __restrict__ a_d, const int* __restrict__ csr_src,
    const float* __restrict__ csr_ea, const int* __restrict__ row_ptr,
    const int* __restrict__ deg, const int* __restrict__ perm,
    const float* __restrict__ scal, int l,
    const float* __restrict__ bias, uint2* __restrict__ hb2)
{
  __shared__ int2 lsw[4][2][32];
  int wid  = threadIdx.x >> 6;
  int lane = threadIdx.x & 63;
  int h    = lane >> 5;
  int c    = lane & 31;
  int idx  = blockIdx.x*8 + wid*2 + h;
  bool live = idx < N_NODES;
  int n = live ? perm[idx] : 0;
  int beg = row_ptr[n];
  int d   = live ? deg[n] : 0;
  float adn = a_d[n];
  float dl  = scal[32 + l];
  int maxd = max(d, __shfl_xor(d, 32, 64));   // partner has ~equal degree now

  float4 acc = make_float4(0.f,0.f,0.f,0.f);
  float ss = 0.f;
  for (int base = 0; base < maxd; base += 32){
    int s = 0; float wgt = 0.f;
    int j = base + c;
    if (j < d){
      int e = beg + j;
      s = csr_src[e];                          // coalesced per half
      float lg = a_s[s] + adn + dl*csr_ea[e];  // unstabilized exp is exact math
      lg = (lg > 0.f) ? lg : SLOPE*lg;
      wgt = __expf(lg);
    }
    int2 pk; pk.x = s; pk.y = __float_as_int(wgt);
    lsw[wid][h][c] = pk;

    int cnt8 = (min(32, maxd - base) + 7) & ~7;
    for (int j0 = 0; j0 < cnt8; j0 += 8){
      int2 sw[8];
      #pragma unroll
      for (int u = 0; u < 8; ++u) sw[u] = lsw[wid][h][j0 + u];
      uint2 xv[8];
      #pragma unroll
      for (int u = 0; u < 8; ++u)
        xv[u] = xtb2[(size_t)sw[u].x*(H/4) + c];
      #pragma unroll
      for (int u = 0; u < 8; ++u){
        float wgt8 = __int_as_float(sw[u].y);
        float x0 = __uint_as_float(xv[u].x << 16);
        float x1 = __uint_as_float(xv[u].x & 0xFFFF0000u);
        float x2 = __uint_as_float(xv[u].y << 16);
        float x3 = __uint_as_float(xv[u].y & 0xFFFF0000u);
        ss    += wgt8;
        acc.x += wgt8 * x0;
        acc.y += wgt8 * x1;
        acc.z += wgt8 * x2;
        acc.w += wgt8 * x3;
      }
    }
  }
  if (!live) return;

  float4 bv = *(const float4*)(bias + c*4);
  float inv = 1.0f / ss;
  acc.x = acc.x*inv + bv.x;
  acc.y = acc.y*inv + bv.y;
  acc.z = acc.z*inv + bv.z;
  acc.w = acc.w*inv + bv.w;
  float sq = acc.x*acc.x + acc.y*acc.y + acc.z*acc.z + acc.w*acc.w;
  #pragma unroll
  for (int off = 16; off > 0; off >>= 1) sq += __shfl_xor(sq, off, 64);  // within half
  float rn = 1.0f / fmaxf(sqrtf(sq), 1e-12f);
  uint2 o;
  o.x = ((unsigned int)rne_bf16(acc.y*rn) << 16) | rne_bf16(acc.x*rn);
  o.y = ((unsigned int)rne_bf16(acc.w*rn) << 16) | rne_bf16(acc.z*rn);
  hb2[(size_t)n*(H/4) + c] = o;
}

// ---- launch -----------------------------------------------------------------
extern "C" void kernel_launch(void* const* d_in, const int* in_sizes, int n_in,
                              void* d_out, int out_size, void* d_ws, size_t ws_size,
                              hipStream_t stream) {
  const int*   x          = (const int*)  d_in[0];
  const int*   edge_index = (const int*)  d_in[1];
  const float* edge_attr  = (const float*)d_in[2];
  const int*   batch      = (const int*)  d_in[3];
  const float* emb        = (const float*)d_in[4];
  const float* gat_W      = (const float*)d_in[5];
  const float* att_src    = (const float*)d_in[6];
  const float* att_dst    = (const float*)d_in[7];
  const float* edge_W     = (const float*)d_in[8];
  const float* att_edge   = (const float*)d_in[9];
  const float* gat_b      = (const float*)d_in[10];
  const float* lin_W      = (const float*)d_in[11];
  const float* lin_b      = (const float*)d_in[12];
  const float* wp_W       = (const float*)d_in[13];
  const float* wp_b       = (const float*)d_in[14];
  float* out = (float*)d_out;

  // workspace layout — 16B-aligned bf16 arrays first, then 4B arrays
  unsigned short* hb  = (unsigned short*)d_ws;          // N*H bf16
  unsigned short* xtb = hb + (size_t)N_NODES*H;         // N*H bf16
  unsigned short* Wt  = xtb + (size_t)N_NODES*H;        // 5*16384 (RNE single plane)
  unsigned short* embb= Wt + 5*16384;                   // NV*H
  float* a_s    = (float*)(embb + NV*H);                // N
  float* a_d    = a_s + N_NODES;                        // N
  float* csr_ea = a_d + N_NODES;                        // E+N
  float* scal   = csr_ea + (N_EDGES + N_NODES);         // SCAL_N (zeroed)
  int*   deg    = (int*)(scal + SCAL_N);                // N (zeroed)
  int*   cursor = deg + N_NODES;                        // N (zeroed)
  int*   row_ptr= cursor + N_NODES;                     // N
  int*   csr_src= row_ptr + N_NODES;                    // E+N
  int*   perm   = csr_src + (N_EDGES + N_NODES);        // N

  int*   hist    = (int*)&scal[64];
  int*   binbase = (int*)&scal[128];
  int*   bincur  = (int*)&scal[192];

  hipMemsetAsync(scal, 0, (size_t)(SCAL_N + 2*N_NODES) * sizeof(float), stream);

  k_prep<<<PB_DEG, 256, 0, stream>>>(
      gat_W, lin_W, Wt, emb, embb, edge_attr, edge_W, att_edge, scal,
      wp_b, out, edge_index, deg);
  k_alloc<<<(N_NODES + 255)/256, 256, 0, stream>>>(
      deg, row_ptr, (int*)&scal[48], hist);
  k_scatter<<<1955, 256, 0, stream>>>(
      edge_index, edge_attr, scal, row_ptr, cursor, csr_src, csr_ea,
      hist, binbase);
  k_perm<<<(N_NODES + 255)/256, 256, 0, stream>>>(deg, binbase, bincur, perm);

  const int gemm_grid = (N_NODES + 127) / 128;
  for (int l = 0; l < NLAYERS; ++l){
    k_gemm<<<gemm_grid, 256, 0, stream>>>(
        (l == 0) ? embb : hb, (l == 0) ? x : nullptr,
        Wt + (size_t)l*16384, xtb,
        att_src + l*H, att_dst + l*H, a_s, a_d,
        nullptr, nullptr, nullptr, 0);
    k_aggregate<<<(N_NODES + 7)/8, 256, 0, stream>>>(
        (const uint2*)xtb, a_s, a_d, csr_src, csr_ea, row_ptr, deg, perm,
        scal, l, gat_b + l*H, (uint2*)hb);
  }
  // dense 1: hb -> xtb (relu+bias, bf16)
  k_gemm<<<gemm_grid, 256, 0, stream>>>(
      hb, nullptr, Wt + (size_t)3*16384, xtb,
      nullptr, nullptr, nullptr, nullptr, lin_b, nullptr, nullptr, 1);
  // dense 2 + fused readout: relu(xtb@W+b)·wp -> atomicAdd out[batch]
  k_gemm<<<gemm_grid, 256, 0, stream>>>(
      xtb, nullptr, Wt + (size_t)4*16384, nullptr,
      wp_W, nullptr, nullptr, nullptr, lin_b + H, batch, out, 2);
}

// Round 16
// 323.907 us; speedup vs baseline: 1.0475x; 1.0475x over previous
//
#include <hip/hip_runtime.h>
#include <math.h>

#define N_NODES 100000
#define N_EDGES 400000
#define NG 2048
#define H 128
#define NV 100
#define NLAYERS 3
#define SLOPE 0.2f

// scal layout (64 floats = 256 B, all zeroed). Cross-XCD rule (R11 lesson):
// never mix atomic and plain stores on one 128B line within a dispatch.
//  [0]      ea_sum        (atomic, k_prep)
//  [32..34] dot_l         (atomic, k_prep)
//  [48]     alloc counter (atomic, k_alloc)
#define SCAL_N 64

typedef __attribute__((ext_vector_type(8))) short bf16x8;
typedef __attribute__((ext_vector_type(4))) float f32x4;

__device__ __forceinline__ float wave_reduce_sum(float v){
  #pragma unroll
  for (int off = 32; off > 0; off >>= 1) v += __shfl_xor(v, off, 64);
  return v;
}
__device__ __forceinline__ unsigned short rne_bf16(float f){
  unsigned int u = __float_as_uint(f);
  u += 0x7FFF + ((u >> 16) & 1);
  return (unsigned short)(u >> 16);
}

// ---- fused prep: convW | convE | out_init | dots | ea_sum | deg -------------
#define PB_CONVW 320                    // 5*16384/256 (single RNE plane)
#define PB_CONVE (PB_CONVW + 50)        // NV*H/256
#define PB_OUT   (PB_CONVE + 8)         // NG/256
#define PB_DOTS  (PB_OUT + 1)           // 3 waves in one block
#define PB_EASUM (PB_DOTS + 256)
#define PB_DEG   (PB_EASUM + 1954)      // (E+N)/256
__global__ __launch_bounds__(256) void k_prep(
    const float* __restrict__ gat_W, const float* __restrict__ lin_W,
    unsigned short* __restrict__ Wf,
    const float* __restrict__ emb, unsigned short* __restrict__ embb,
    const float* __restrict__ ea, const float* __restrict__ ew,
    const float* __restrict__ ae, float* __restrict__ scal,
    const float* __restrict__ wp_b, float* __restrict__ out,
    const int* __restrict__ ei, int* __restrict__ deg)
{
  int b = blockIdx.x, tid = threadIdx.x;
  if (b < PB_CONVW){
    // W -> RNE bf16, MFMA B-fragment order:
    // idx = m*16384 + k0i*4096 + ct*512 + lane*8 + j
    // k = k0i*32 + (lane>>4)*8 + j, n = ct*16 + (lane&15)
    int i = b*256 + tid;
    int m   = i >> 14;
    int r   = i & 16383;
    int k0i = r >> 12;
    int r3  = r & 4095;
    int ct  = r3 >> 9;
    int r4  = r3 & 511;
    int lane= r4 >> 3;
    int j   = r4 & 7;
    int q = lane >> 4, ln = lane & 15;
    int k = k0i*32 + q*8 + j;
    int n = ct*16 + ln;
    const float* src = (m < 3) ? (gat_W + m*16384) : (lin_W + (m-3)*16384);
    Wf[i] = rne_bf16(src[k*H + n]);
  } else if (b < PB_CONVE){
    int i = (b - PB_CONVW)*256 + tid;
    if (i < NV*H) embb[i] = rne_bf16(emb[i]);
  } else if (b < PB_OUT){
    int g = (b - PB_CONVE)*256 + tid;
    if (g < NG) out[g] = wp_b[0];
  } else if (b < PB_DOTS){
    int l = tid >> 6, ln = tid & 63;
    if (l < NLAYERS){
      float p = ew[l*H + ln]*ae[l*H + ln] + ew[l*H + ln + 64]*ae[l*H + ln + 64];
      p = wave_reduce_sum(p);
      if (ln == 0) atomicAdd(&scal[32 + l], p);
    }
  } else if (b < PB_EASUM){
    int i = (b - PB_DOTS)*256 + tid;
    int stride = 256*256;
    float v = 0.f;
    for (; i < N_EDGES; i += stride) v += ea[i];
    v = wave_reduce_sum(v);
    if ((tid & 63) == 0) atomicAdd(&scal[0], v);
  } else {
    int i = (b - PB_EASUM)*256 + tid;
    if (i < N_EDGES + N_NODES){
      int d = (i < N_EDGES) ? ei[N_EDGES + i] : (i - N_EDGES);
      atomicAdd(&deg[d], 1);
    }
  }
}

// block scan + one atomic per block (CSR range order across nodes irrelevant)
__global__ __launch_bounds__(256) void k_alloc(
    const int* __restrict__ deg, int* __restrict__ row_ptr, int* __restrict__ counter){
  __shared__ int wsum[4];
  __shared__ int base;
  int n = blockIdx.x * 256 + threadIdx.x;
  int d = (n < N_NODES) ? deg[n] : 0;
  int lane = threadIdx.x & 63, wid = threadIdx.x >> 6;
  int v = d;
  #pragma unroll
  for (int off = 1; off < 64; off <<= 1){
    int u = __shfl_up(v, off, 64);
    if (lane >= off) v += u;
  }
  if (lane == 63) wsum[wid] = v;
  __syncthreads();
  if (threadIdx.x == 0){
    int t0 = wsum[0], t1 = wsum[1], t2 = wsum[2], t3 = wsum[3];
    base = atomicAdd(counter, t0 + t1 + t2 + t3);
    wsum[0] = 0; wsum[1] = t0; wsum[2] = t0 + t1; wsum[3] = t0 + t1 + t2;
  }
  __syncthreads();
  if (n < N_NODES) row_ptr[n] = base + wsum[wid] + (v - d);
}

__global__ void k_scatter(const int* __restrict__ ei, const float* __restrict__ ea,
                          const float* __restrict__ scal, const int* __restrict__ row_ptr,
                          int* __restrict__ cursor, int* __restrict__ csr_src,
                          float* __restrict__ csr_ea){
  int i = blockIdx.x * blockDim.x + threadIdx.x;
  if (i >= N_EDGES + N_NODES) return;
  int s, d; float v;
  if (i < N_EDGES){ s = ei[i]; d = ei[N_EDGES + i]; v = ea[i]; }
  else            { s = d = i - N_EDGES; v = scal[0] * (1.0f / N_EDGES); }  // ea_mean
  int pos = row_ptr[d] + atomicAdd(&cursor[d], 1);
  csr_src[pos] = s;
  csr_ea[pos]  = v;
}

// ---- MFMA GEMM: bf16 A, RNE-bf16 W (single term), 32KB W in LDS -------------
// Block = 256 thr = 4 waves; block tile 128 rows; wave tile 32 rows (2 m-tiles);
// 4 blocks/CU. mode 0: Cb=bf16(acc), a_s/a_d epilogue; mode 1: relu+bias;
// mode 2: relu(acc+bias)·att1 -> atomicAdd out[batch[row]]
__global__ __launch_bounds__(256, 4) void k_gemm(
    const unsigned short* __restrict__ Ab, const int* __restrict__ xmap,
    const unsigned short* __restrict__ Wf,      // fragment-ordered, 16384 ushorts
    unsigned short* __restrict__ Cb,
    const float* __restrict__ att1, const float* __restrict__ att2,
    float* __restrict__ a_s_out, float* __restrict__ a_d_out,
    const float* __restrict__ bias,
    const int* __restrict__ batch, float* __restrict__ out,
    int mode)
{
  __shared__ unsigned short lw[16384];   // 32 KB single plane
  int tid  = threadIdx.x;
  int w    = tid >> 6;
  int lane = tid & 63;
  int q    = lane >> 4;
  int ln   = lane & 15;
  int waveRow = blockIdx.x*128 + w*32;

  bf16x8 af[2][4];
  #pragma unroll
  for (int m = 0; m < 2; ++m){
    int r = waveRow + m*16 + ln;
    if (r >= N_NODES) r = N_NODES - 1;
    if (xmap) r = xmap[r];
    const unsigned short* Ar = Ab + (size_t)r*H;
    #pragma unroll
    for (int k0i = 0; k0i < 4; ++k0i)
      af[m][k0i] = *(const bf16x8*)(Ar + k0i*32 + q*8);
  }

  // stage W (32 KB, 16B/thread x 8)
  #pragma unroll
  for (int i = 0; i < 8; ++i){
    int idx = (i*256 + tid) * 8;
    *(bf16x8*)(lw + idx) = *(const bf16x8*)(Wf + idx);
  }
  __syncthreads();

  f32x4 acc[2][8];
  #pragma unroll
  for (int m = 0; m < 2; ++m)
    #pragma unroll
    for (int ct = 0; ct < 8; ++ct) acc[m][ct] = (f32x4){0.f,0.f,0.f,0.f};

  #pragma unroll
  for (int k0i = 0; k0i < 4; ++k0i){
    #pragma unroll
    for (int ct = 0; ct < 8; ++ct){
      bf16x8 bw = *(const bf16x8*)(lw + k0i*4096 + ct*512 + lane*8);
      #pragma unroll
      for (int m = 0; m < 2; ++m)
        acc[m][ct] = __builtin_amdgcn_mfma_f32_16x16x32_bf16(af[m][k0i], bw, acc[m][ct], 0,0,0);
    }
  }

  // C/D layout: col = ct*16 + ln, row = (m-tile base) + q*4 + r
  if (mode == 0){
    float as_l[8], ad_l[8];
    #pragma unroll
    for (int ct = 0; ct < 8; ++ct){ as_l[ct] = att1[ct*16+ln]; ad_l[ct] = att2[ct*16+ln]; }
    #pragma unroll
    for (int m = 0; m < 2; ++m){
      #pragma unroll
      for (int r = 0; r < 4; ++r){
        int grow = waveRow + m*16 + q*4 + r;
        bool ok = grow < N_NODES;
        float ps = 0.f, pd = 0.f;
        #pragma unroll
        for (int ct = 0; ct < 8; ++ct){
          float v = acc[m][ct][r];
          if (ok) Cb[(size_t)grow*H + ct*16 + ln] = rne_bf16(v);
          ps += v * as_l[ct]; pd += v * ad_l[ct];
        }
        #pragma unroll
        for (int mk = 8; mk > 0; mk >>= 1){
          ps += __shfl_xor(ps, mk, 64);
          pd += __shfl_xor(pd, mk, 64);
        }
        if (ok && ln == 0){ a_s_out[grow] = ps; a_d_out[grow] = pd; }
      }
    }
  } else if (mode == 1){
    float b_l[8];
    #pragma unroll
    for (int ct = 0; ct < 8; ++ct) b_l[ct] = bias[ct*16+ln];
    #pragma unroll
    for (int m = 0; m < 2; ++m){
      #pragma unroll
      for (int r = 0; r < 4; ++r){
        int grow = waveRow + m*16 + q*4 + r;
        if (grow >= N_NODES) continue;
        #pragma unroll
        for (int ct = 0; ct < 8; ++ct)
          Cb[(size_t)grow*H + ct*16 + ln] = rne_bf16(fmaxf(acc[m][ct][r] + b_l[ct], 0.f));
      }
    }
  } else {
    float b_l[8], wp_l[8];
    #pragma unroll
    for (int ct = 0; ct < 8; ++ct){ b_l[ct] = bias[ct*16+ln]; wp_l[ct] = att1[ct*16+ln]; }
    #pragma unroll
    for (int m = 0; m < 2; ++m){
      #pragma unroll
      for (int r = 0; r < 4; ++r){
        int grow = waveRow + m*16 + q*4 + r;
        bool ok = grow < N_NODES;
        float ps = 0.f;
        #pragma unroll
        for (int ct = 0; ct < 8; ++ct)
          ps += fmaxf(acc[m][ct][r] + b_l[ct], 0.f) * wp_l[ct];
        #pragma unroll
        for (int mk = 8; mk > 0; mk >>= 1) ps += __shfl_xor(ps, mk, 64);
        if (ok && ln == 0) atomicAdd(&out[batch[grow]], ps);
      }
    }
  }
}

// ---- aggregate: TWO nodes per wave, 4 cols/lane (uint2 = 4 bf16) ------------
// R14 structure (natural node order -> coalesced hb writes). Half h = lane>>5
// owns node n = blk*8 + wid*2 + h; lane c = lane&31 covers cols 4c..4c+3.
// Prologue stages (src, w) into LDS with w=0 pads -> maskless hot loop:
// 8 ds_read_b64 + 8 independent dwordx2 gathers + FMAs per 16 node-edges.
__global__ __launch_bounds__(256, 4) void k_aggregate(
    const uint2* __restrict__ xtb2, const float* __restrict__ a_s,
    const float* __restrict__ a_d, const int* __restrict__ csr_src,
    const float* __restrict__ csr_ea, const int* __restrict__ row_ptr,
    const int* __restrict__ deg, const float* __restrict__ scal, int l,
    const float* __restrict__ bias, uint2* __restrict__ hb2)
{
  __shared__ int2 lsw[4][2][32];
  int wid  = threadIdx.x >> 6;
  int lane = threadIdx.x & 63;
  int h    = lane >> 5;
  int c    = lane & 31;
  int n    = blockIdx.x*8 + wid*2 + h;
  if (n >= N_NODES) return;
  int beg = row_ptr[n];
  int d   = deg[n];              // >= 1 (self loop)
  float adn = a_d[n];
  float dl  = scal[32 + l];
  int maxd = max(d, __shfl_xor(d, 32, 64));   // shared loop bound for both halves

  float4 acc = make_float4(0.f,0.f,0.f,0.f);
  float ss = 0.f;
  for (int base = 0; base < maxd; base += 32){
    int s = 0; float wgt = 0.f;
    int j = base + c;
    if (j < d){
      int e = beg + j;
      s = csr_src[e];                          // coalesced per half
      float lg = a_s[s] + adn + dl*csr_ea[e];  // unstabilized exp is exact math
      lg = (lg > 0.f) ? lg : SLOPE*lg;
      wgt = __expf(lg);
    }
    int2 pk; pk.x = s; pk.y = __float_as_int(wgt);
    lsw[wid][h][c] = pk;

    int cnt8 = (min(32, maxd - base) + 7) & ~7;
    for (int j0 = 0; j0 < cnt8; j0 += 8){
      int2 sw[8];
      #pragma unroll
      for (int u = 0; u < 8; ++u) sw[u] = lsw[wid][h][j0 + u];
      uint2 xv[8];
      #pragma unroll
      for (int u = 0; u < 8; ++u)
        xv[u] = xtb2[(size_t)sw[u].x*(H/4) + c];
      #pragma unroll
      for (int u = 0; u < 8; ++u){
        float wgt8 = __int_as_float(sw[u].y);
        float x0 = __uint_as_float(xv[u].x << 16);
        float x1 = __uint_as_float(xv[u].x & 0xFFFF0000u);
        float x2 = __uint_as_float(xv[u].y << 16);
        float x3 = __uint_as_float(xv[u].y & 0xFFFF0000u);
        ss    += wgt8;
        acc.x += wgt8 * x0;
        acc.y += wgt8 * x1;
        acc.z += wgt8 * x2;
        acc.w += wgt8 * x3;
      }
    }
  }

  float4 bv = *(const float4*)(bias + c*4);
  float inv = 1.0f / ss;
  acc.x = acc.x*inv + bv.x;
  acc.y = acc.y*inv + bv.y;
  acc.z = acc.z*inv + bv.z;
  acc.w = acc.w*inv + bv.w;
  float sq = acc.x*acc.x + acc.y*acc.y + acc.z*acc.z + acc.w*acc.w;
  #pragma unroll
  for (int off = 16; off > 0; off >>= 1) sq += __shfl_xor(sq, off, 64);  // within half
  float rn = 1.0f / fmaxf(sqrtf(sq), 1e-12f);
  uint2 o;
  o.x = ((unsigned int)rne_bf16(acc.y*rn) << 16) | rne_bf16(acc.x*rn);
  o.y = ((unsigned int)rne_bf16(acc.w*rn) << 16) | rne_bf16(acc.z*rn);
  hb2[(size_t)n*(H/4) + c] = o;
}

// ---- launch -----------------------------------------------------------------
extern "C" void kernel_launch(void* const* d_in, const int* in_sizes, int n_in,
                              void* d_out, int out_size, void* d_ws, size_t ws_size,
                              hipStream_t stream) {
  const int*   x          = (const int*)  d_in[0];
  const int*   edge_index = (const int*)  d_in[1];
  const float* edge_attr  = (const float*)d_in[2];
  const int*   batch      = (const int*)  d_in[3];
  const float* emb        = (const float*)d_in[4];
  const float* gat_W      = (const float*)d_in[5];
  const float* att_src    = (const float*)d_in[6];
  const float* att_dst    = (const float*)d_in[7];
  const float* edge_W     = (const float*)d_in[8];
  const float* att_edge   = (const float*)d_in[9];
  const float* gat_b      = (const float*)d_in[10];
  const float* lin_W      = (const float*)d_in[11];
  const float* lin_b      = (const float*)d_in[12];
  const float* wp_W       = (const float*)d_in[13];
  const float* wp_b       = (const float*)d_in[14];
  float* out = (float*)d_out;

  // workspace layout — 16B-aligned bf16 arrays first, then 4B arrays
  unsigned short* hb  = (unsigned short*)d_ws;          // N*H bf16
  unsigned short* xtb = hb + (size_t)N_NODES*H;         // N*H bf16
  unsigned short* Wt  = xtb + (size_t)N_NODES*H;        // 5*16384 (RNE single plane)
  unsigned short* embb= Wt + 5*16384;                   // NV*H
  float* a_s    = (float*)(embb + NV*H);                // N
  float* a_d    = a_s + N_NODES;                        // N
  float* csr_ea = a_d + N_NODES;                        // E+N
  float* scal   = csr_ea + (N_EDGES + N_NODES);         // SCAL_N (zeroed)
  int*   deg    = (int*)(scal + SCAL_N);                // N (zeroed)
  int*   cursor = deg + N_NODES;                        // N (zeroed)
  int*   row_ptr= cursor + N_NODES;                     // N
  int*   csr_src= row_ptr + N_NODES;                    // E+N

  hipMemsetAsync(scal, 0, (size_t)(SCAL_N + 2*N_NODES) * sizeof(float), stream);

  k_prep<<<PB_DEG, 256, 0, stream>>>(
      gat_W, lin_W, Wt, emb, embb, edge_attr, edge_W, att_edge, scal,
      wp_b, out, edge_index, deg);
  k_alloc<<<(N_NODES + 255)/256, 256, 0, stream>>>(deg, row_ptr, (int*)&scal[48]);
  k_scatter<<<(N_EDGES + N_NODES + 255)/256, 256, 0, stream>>>(
      edge_index, edge_attr, scal, row_ptr, cursor, csr_src, csr_ea);

  const int gemm_grid = (N_NODES + 127) / 128;
  for (int l = 0; l < NLAYERS; ++l){
    k_gemm<<<gemm_grid, 256, 0, stream>>>(
        (l == 0) ? embb : hb, (l == 0) ? x : nullptr,
        Wt + (size_t)l*16384, xtb,
        att_src + l*H, att_dst + l*H, a_s, a_d,
        nullptr, nullptr, nullptr, 0);
    k_aggregate<<<(N_NODES + 7)/8, 256, 0, stream>>>(
        (const uint2*)xtb, a_s, a_d, csr_src, csr_ea, row_ptr, deg,
        scal, l, gat_b + l*H, (uint2*)hb);
  }
  // dense 1: hb -> xtb (relu+bias, bf16)
  k_gemm<<<gemm_grid, 256, 0, stream>>>(
      hb, nullptr, Wt + (size_t)3*16384, xtb,
      nullptr, nullptr, nullptr, nullptr, lin_b, nullptr, nullptr, 1);
  // dense 2 + fused readout: relu(xtb@W+b)·wp -> atomicAdd out[batch]
  k_gemm<<<gemm_grid, 256, 0, stream>>>(
      xtb, nullptr, Wt + (size_t)4*16384, nullptr,
      wp_W, nullptr, nullptr, nullptr, lin_b + H, batch, out, 2);
}

// Round 17
// 322.674 us; speedup vs baseline: 1.0515x; 1.0038x over previous
//
#include <hip/hip_runtime.h>
#include <math.h>

#define N_NODES 100000
#define N_EDGES 400000
#define NG 2048
#define H 128
#define NV 100
#define NLAYERS 3
#define SLOPE 0.2f

// scal layout (64 floats = 256 B, all zeroed). Cross-XCD rule (R11 lesson):
// never mix atomic and plain stores on one 128B line within a dispatch.
//  [0]      ea_sum        (atomic, k_prep)
//  [32..34] dot_l         (atomic, k_prep)
//  [48]     alloc counter (atomic, k_alloc)
#define SCAL_N 64

typedef __attribute__((ext_vector_type(8))) short bf16x8;
typedef __attribute__((ext_vector_type(4))) float f32x4;

__device__ __forceinline__ float wave_reduce_sum(float v){
  #pragma unroll
  for (int off = 32; off > 0; off >>= 1) v += __shfl_xor(v, off, 64);
  return v;
}
__device__ __forceinline__ unsigned short rne_bf16(float f){
  unsigned int u = __float_as_uint(f);
  u += 0x7FFF + ((u >> 16) & 1);
  return (unsigned short)(u >> 16);
}

// ---- fused prep: convW | convE | out_init | dots | ea_sum | deg -------------
#define PB_CONVW 320                    // 5*16384/256 (single RNE plane)
#define PB_CONVE (PB_CONVW + 50)        // NV*H/256
#define PB_OUT   (PB_CONVE + 8)         // NG/256
#define PB_DOTS  (PB_OUT + 1)           // 3 waves in one block
#define PB_EASUM (PB_DOTS + 256)
#define PB_DEG   (PB_EASUM + 1954)      // (E+N)/256
__global__ __launch_bounds__(256) void k_prep(
    const float* __restrict__ gat_W, const float* __restrict__ lin_W,
    unsigned short* __restrict__ Wf,
    const float* __restrict__ emb, unsigned short* __restrict__ embb,
    const float* __restrict__ ea, const float* __restrict__ ew,
    const float* __restrict__ ae, float* __restrict__ scal,
    const float* __restrict__ wp_b, float* __restrict__ out,
    const int* __restrict__ ei, int* __restrict__ deg)
{
  int b = blockIdx.x, tid = threadIdx.x;
  if (b < PB_CONVW){
    // W -> RNE bf16, MFMA B-fragment order:
    // idx = m*16384 + k0i*4096 + ct*512 + lane*8 + j
    // k = k0i*32 + (lane>>4)*8 + j, n = ct*16 + (lane&15)
    int i = b*256 + tid;
    int m   = i >> 14;
    int r   = i & 16383;
    int k0i = r >> 12;
    int r3  = r & 4095;
    int ct  = r3 >> 9;
    int r4  = r3 & 511;
    int lane= r4 >> 3;
    int j   = r4 & 7;
    int q = lane >> 4, ln = lane & 15;
    int k = k0i*32 + q*8 + j;
    int n = ct*16 + ln;
    const float* src = (m < 3) ? (gat_W + m*16384) : (lin_W + (m-3)*16384);
    Wf[i] = rne_bf16(src[k*H + n]);
  } else if (b < PB_CONVE){
    int i = (b - PB_CONVW)*256 + tid;
    if (i < NV*H) embb[i] = rne_bf16(emb[i]);
  } else if (b < PB_OUT){
    int g = (b - PB_CONVE)*256 + tid;
    if (g < NG) out[g] = wp_b[0];
  } else if (b < PB_DOTS){
    int l = tid >> 6, ln = tid & 63;
    if (l < NLAYERS){
      float p = ew[l*H + ln]*ae[l*H + ln] + ew[l*H + ln + 64]*ae[l*H + ln + 64];
      p = wave_reduce_sum(p);
      if (ln == 0) atomicAdd(&scal[32 + l], p);
    }
  } else if (b < PB_EASUM){
    int i = (b - PB_DOTS)*256 + tid;
    int stride = 256*256;
    float v = 0.f;
    for (; i < N_EDGES; i += stride) v += ea[i];
    v = wave_reduce_sum(v);
    if ((tid & 63) == 0) atomicAdd(&scal[0], v);
  } else {
    int i = (b - PB_EASUM)*256 + tid;
    if (i < N_EDGES + N_NODES){
      int d = (i < N_EDGES) ? ei[N_EDGES + i] : (i - N_EDGES);
      atomicAdd(&deg[d], 1);
    }
  }
}

// block scan + one atomic per block (CSR range order across nodes irrelevant)
__global__ __launch_bounds__(256) void k_alloc(
    const int* __restrict__ deg, int* __restrict__ row_ptr, int* __restrict__ counter){
  __shared__ int wsum[4];
  __shared__ int base;
  int n = blockIdx.x * 256 + threadIdx.x;
  int d = (n < N_NODES) ? deg[n] : 0;
  int lane = threadIdx.x & 63, wid = threadIdx.x >> 6;
  int v = d;
  #pragma unroll
  for (int off = 1; off < 64; off <<= 1){
    int u = __shfl_up(v, off, 64);
    if (lane >= off) v += u;
  }
  if (lane == 63) wsum[wid] = v;
  __syncthreads();
  if (threadIdx.x == 0){
    int t0 = wsum[0], t1 = wsum[1], t2 = wsum[2], t3 = wsum[3];
    base = atomicAdd(counter, t0 + t1 + t2 + t3);
    wsum[0] = 0; wsum[1] = t0; wsum[2] = t0 + t1; wsum[3] = t0 + t1 + t2;
  }
  __syncthreads();
  if (n < N_NODES) row_ptr[n] = base + wsum[wid] + (v - d);
}

__global__ void k_scatter(const int* __restrict__ ei, const float* __restrict__ ea,
                          const float* __restrict__ scal, const int* __restrict__ row_ptr,
                          int* __restrict__ cursor, int* __restrict__ csr_src,
                          float* __restrict__ csr_ea){
  int i = blockIdx.x * blockDim.x + threadIdx.x;
  if (i >= N_EDGES + N_NODES) return;
  int s, d; float v;
  if (i < N_EDGES){ s = ei[i]; d = ei[N_EDGES + i]; v = ea[i]; }
  else            { s = d = i - N_EDGES; v = scal[0] * (1.0f / N_EDGES); }  // ea_mean
  int pos = row_ptr[d] + atomicAdd(&cursor[d], 1);
  csr_src[pos] = s;
  csr_ea[pos]  = v;
}

// ---- MFMA GEMM: bf16 A, RNE-bf16 W, 32KB W in LDS via global_load_lds -------
// Block = 256 thr = 4 waves; block tile 128 rows; wave tile 32 rows (2 m-tiles);
// 4 blocks/CU. W staged with async direct-to-LDS 16B ops (no VGPR round-trip);
// LDS dest is wave-uniform base + lane*16 as required (guide m104/m108).
// mode 0: Cb=bf16(acc), a_s/a_d epilogue; mode 1: relu+bias;
// mode 2: relu(acc+bias)·att1 -> atomicAdd out[batch[row]]
__global__ __launch_bounds__(256, 4) void k_gemm(
    const unsigned short* __restrict__ Ab, const int* __restrict__ xmap,
    const unsigned short* __restrict__ Wf,      // fragment-ordered, 16384 ushorts
    unsigned short* __restrict__ Cb,
    const float* __restrict__ att1, const float* __restrict__ att2,
    float* __restrict__ a_s_out, float* __restrict__ a_d_out,
    const float* __restrict__ bias,
    const int* __restrict__ batch, float* __restrict__ out,
    int mode)
{
  __shared__ unsigned short lw[16384];   // 32 KB single plane
  int tid  = threadIdx.x;
  int w    = tid >> 6;
  int lane = tid & 63;
  int q    = lane >> 4;
  int ln   = lane & 15;
  int waveRow = blockIdx.x*128 + w*32;

  // async stage W: 8 iters x (64 lanes x 16B) per wave, wave-uniform LDS base
  #pragma unroll
  for (int i = 0; i < 8; ++i){
    int base = (i*256 + w*64) * 8;               // ushort offset, wave-uniform
    __builtin_amdgcn_global_load_lds(
        (const __attribute__((address_space(1))) unsigned int*)(Wf + base + lane*8),
        (__attribute__((address_space(3))) unsigned int*)(lw + base),
        16, 0, 0);
  }

  // A fragments (overlap with W staging in the same vmcnt window)
  bf16x8 af[2][4];
  #pragma unroll
  for (int m = 0; m < 2; ++m){
    int r = waveRow + m*16 + ln;
    if (r >= N_NODES) r = N_NODES - 1;
    if (xmap) r = xmap[r];
    const unsigned short* Ar = Ab + (size_t)r*H;
    #pragma unroll
    for (int k0i = 0; k0i < 4; ++k0i)
      af[m][k0i] = *(const bf16x8*)(Ar + k0i*32 + q*8);
  }
  __syncthreads();   // drains vmcnt (incl. global_load_lds) before ds_read

  f32x4 acc[2][8];
  #pragma unroll
  for (int m = 0; m < 2; ++m)
    #pragma unroll
    for (int ct = 0; ct < 8; ++ct) acc[m][ct] = (f32x4){0.f,0.f,0.f,0.f};

  #pragma unroll
  for (int k0i = 0; k0i < 4; ++k0i){
    #pragma unroll
    for (int ct = 0; ct < 8; ++ct){
      bf16x8 bw = *(const bf16x8*)(lw + k0i*4096 + ct*512 + lane*8);
      #pragma unroll
      for (int m = 0; m < 2; ++m)
        acc[m][ct] = __builtin_amdgcn_mfma_f32_16x16x32_bf16(af[m][k0i], bw, acc[m][ct], 0,0,0);
    }
  }

  // C/D layout: col = ct*16 + ln, row = (m-tile base) + q*4 + r
  if (mode == 0){
    float as_l[8], ad_l[8];
    #pragma unroll
    for (int ct = 0; ct < 8; ++ct){ as_l[ct] = att1[ct*16+ln]; ad_l[ct] = att2[ct*16+ln]; }
    #pragma unroll
    for (int m = 0; m < 2; ++m){
      #pragma unroll
      for (int r = 0; r < 4; ++r){
        int grow = waveRow + m*16 + q*4 + r;
        bool ok = grow < N_NODES;
        float ps = 0.f, pd = 0.f;
        #pragma unroll
        for (int ct = 0; ct < 8; ++ct){
          float v = acc[m][ct][r];
          if (ok) Cb[(size_t)grow*H + ct*16 + ln] = rne_bf16(v);
          ps += v * as_l[ct]; pd += v * ad_l[ct];
        }
        #pragma unroll
        for (int mk = 8; mk > 0; mk >>= 1){
          ps += __shfl_xor(ps, mk, 64);
          pd += __shfl_xor(pd, mk, 64);
        }
        if (ok && ln == 0){ a_s_out[grow] = ps; a_d_out[grow] = pd; }
      }
    }
  } else if (mode == 1){
    float b_l[8];
    #pragma unroll
    for (int ct = 0; ct < 8; ++ct) b_l[ct] = bias[ct*16+ln];
    #pragma unroll
    for (int m = 0; m < 2; ++m){
      #pragma unroll
      for (int r = 0; r < 4; ++r){
        int grow = waveRow + m*16 + q*4 + r;
        if (grow >= N_NODES) continue;
        #pragma unroll
        for (int ct = 0; ct < 8; ++ct)
          Cb[(size_t)grow*H + ct*16 + ln] = rne_bf16(fmaxf(acc[m][ct][r] + b_l[ct], 0.f));
      }
    }
  } else {
    float b_l[8], wp_l[8];
    #pragma unroll
    for (int ct = 0; ct < 8; ++ct){ b_l[ct] = bias[ct*16+ln]; wp_l[ct] = att1[ct*16+ln]; }
    #pragma unroll
    for (int m = 0; m < 2; ++m){
      #pragma unroll
      for (int r = 0; r < 4; ++r){
        int grow = waveRow + m*16 + q*4 + r;
        bool ok = grow < N_NODES;
        float ps = 0.f;
        #pragma unroll
        for (int ct = 0; ct < 8; ++ct)
          ps += fmaxf(acc[m][ct][r] + b_l[ct], 0.f) * wp_l[ct];
        #pragma unroll
        for (int mk = 8; mk > 0; mk >>= 1) ps += __shfl_xor(ps, mk, 64);
        if (ok && ln == 0) atomicAdd(&out[batch[grow]], ps);
      }
    }
  }
}

// ---- aggregate: TWO nodes per wave, 4 cols/lane (uint2 = 4 bf16) ------------
// R14 structure (natural node order -> coalesced hb writes). Half h = lane>>5
// owns node n = blk*8 + wid*2 + h; lane c = lane&31 covers cols 4c..4c+3.
// Prologue stages (src, w) into LDS with w=0 pads -> maskless hot loop:
// 8 ds_read_b64 + 8 independent dwordx2 gathers + FMAs per 16 node-edges.
__global__ __launch_bounds__(256, 4) void k_aggregate(
    const uint2* __restrict__ xtb2, const float* __restrict__ a_s,
    const float* __restrict__ a_d, const int* __restrict__ csr_src,
    const float* __restrict__ csr_ea, const int* __restrict__ row_ptr,
    const int* __restrict__ deg, const float* __restrict__ scal, int l,
    const float* __restrict__ bias, uint2* __restrict__ hb2)
{
  __shared__ int2 lsw[4][2][32];
  int wid  = threadIdx.x >> 6;
  int lane = threadIdx.x & 63;
  int h    = lane >> 5;
  int c    = lane & 31;
  int n    = blockIdx.x*8 + wid*2 + h;
  if (n >= N_NODES) return;
  int beg = row_ptr[n];
  int d   = deg[n];              // >= 1 (self loop)
  float adn = a_d[n];
  float dl  = scal[32 + l];
  int maxd = max(d, __shfl_xor(d, 32, 64));   // shared loop bound for both halves

  float4 acc = make_float4(0.f,0.f,0.f,0.f);
  float ss = 0.f;
  for (int base = 0; base < maxd; base += 32){
    int s = 0; float wgt = 0.f;
    int j = base + c;
    if (j < d){
      int e = beg + j;
      s = csr_src[e];                          // coalesced per half
      float lg = a_s[s] + adn + dl*csr_ea[e];  // unstabilized exp is exact math
      lg = (lg > 0.f) ? lg : SLOPE*lg;
      wgt = __expf(lg);
    }
    int2 pk; pk.x = s; pk.y = __float_as_int(wgt);
    lsw[wid][h][c] = pk;

    int cnt8 = (min(32, maxd - base) + 7) & ~7;
    for (int j0 = 0; j0 < cnt8; j0 += 8){
      int2 sw[8];
      #pragma unroll
      for (int u = 0; u < 8; ++u) sw[u] = lsw[wid][h][j0 + u];
      uint2 xv[8];
      #pragma unroll
      for (int u = 0; u < 8; ++u)
        xv[u] = xtb2[(size_t)sw[u].x*(H/4) + c];
      #pragma unroll
      for (int u = 0; u < 8; ++u){
        float wgt8 = __int_as_float(sw[u].y);
        float x0 = __uint_as_float(xv[u].x << 16);
        float x1 = __uint_as_float(xv[u].x & 0xFFFF0000u);
        float x2 = __uint_as_float(xv[u].y << 16);
        float x3 = __uint_as_float(xv[u].y & 0xFFFF0000u);
        ss    += wgt8;
        acc.x += wgt8 * x0;
        acc.y += wgt8 * x1;
        acc.z += wgt8 * x2;
        acc.w += wgt8 * x3;
      }
    }
  }

  float4 bv = *(const float4*)(bias + c*4);
  float inv = 1.0f / ss;
  acc.x = acc.x*inv + bv.x;
  acc.y = acc.y*inv + bv.y;
  acc.z = acc.z*inv + bv.z;
  acc.w = acc.w*inv + bv.w;
  float sq = acc.x*acc.x + acc.y*acc.y + acc.z*acc.z + acc.w*acc.w;
  #pragma unroll
  for (int off = 16; off > 0; off >>= 1) sq += __shfl_xor(sq, off, 64);  // within half
  float rn = 1.0f / fmaxf(sqrtf(sq), 1e-12f);
  uint2 o;
  o.x = ((unsigned int)rne_bf16(acc.y*rn) << 16) | rne_bf16(acc.x*rn);
  o.y = ((unsigned int)rne_bf16(acc.w*rn) << 16) | rne_bf16(acc.z*rn);
  hb2[(size_t)n*(H/4) + c] = o;
}

// ---- launch -----------------------------------------------------------------
extern "C" void kernel_launch(void* const* d_in, const int* in_sizes, int n_in,
                              void* d_out, int out_size, void* d_ws, size_t ws_size,
                              hipStream_t stream) {
  const int*   x          = (const int*)  d_in[0];
  const int*   edge_index = (const int*)  d_in[1];
  const float* edge_attr  = (const float*)d_in[2];
  const int*   batch      = (const int*)  d_in[3];
  const float* emb        = (const float*)d_in[4];
  const float* gat_W      = (const float*)d_in[5];
  const float* att_src    = (const float*)d_in[6];
  const float* att_dst    = (const float*)d_in[7];
  const float* edge_W     = (const float*)d_in[8];
  const float* att_edge   = (const float*)d_in[9];
  const float* gat_b      = (const float*)d_in[10];
  const float* lin_W      = (const float*)d_in[11];
  const float* lin_b      = (const float*)d_in[12];
  const float* wp_W       = (const float*)d_in[13];
  const float* wp_b       = (const float*)d_in[14];
  float* out = (float*)d_out;

  // workspace layout — 16B-aligned bf16 arrays first, then 4B arrays
  unsigned short* hb  = (unsigned short*)d_ws;          // N*H bf16
  unsigned short* xtb = hb + (size_t)N_NODES*H;         // N*H bf16
  unsigned short* Wt  = xtb + (size_t)N_NODES*H;        // 5*16384 (RNE single plane)
  unsigned short* embb= Wt + 5*16384;                   // NV*H
  float* a_s    = (float*)(embb + NV*H);                // N
  float* a_d    = a_s + N_NODES;                        // N
  float* csr_ea = a_d + N_NODES;                        // E+N
  float* scal   = csr_ea + (N_EDGES + N_NODES);         // SCAL_N (zeroed)
  int*   deg    = (int*)(scal + SCAL_N);                // N (zeroed)
  int*   cursor = deg + N_NODES;                        // N (zeroed)
  int*   row_ptr= cursor + N_NODES;                     // N
  int*   csr_src= row_ptr + N_NODES;                    // E+N

  hipMemsetAsync(scal, 0, (size_t)(SCAL_N + 2*N_NODES) * sizeof(float), stream);

  k_prep<<<PB_DEG, 256, 0, stream>>>(
      gat_W, lin_W, Wt, emb, embb, edge_attr, edge_W, att_edge, scal,
      wp_b, out, edge_index, deg);
  k_alloc<<<(N_NODES + 255)/256, 256, 0, stream>>>(deg, row_ptr, (int*)&scal[48]);
  k_scatter<<<(N_EDGES + N_NODES + 255)/256, 256, 0, stream>>>(
      edge_index, edge_attr, scal, row_ptr, cursor, csr_src, csr_ea);

  const int gemm_grid = (N_NODES + 127) / 128;
  for (int l = 0; l < NLAYERS; ++l){
    k_gemm<<<gemm_grid, 256, 0, stream>>>(
        (l == 0) ? embb : hb, (l == 0) ? x : nullptr,
        Wt + (size_t)l*16384, xtb,
        att_src + l*H, att_dst + l*H, a_s, a_d,
        nullptr, nullptr, nullptr, 0);
    k_aggregate<<<(N_NODES + 7)/8, 256, 0, stream>>>(
        (const uint2*)xtb, a_s, a_d, csr_src, csr_ea, row_ptr, deg,
        scal, l, gat_b + l*H, (uint2*)hb);
  }
  // dense 1: hb -> xtb (relu+bias, bf16)
  k_gemm<<<gemm_grid, 256, 0, stream>>>(
      hb, nullptr, Wt + (size_t)3*16384, xtb,
      nullptr, nullptr, nullptr, nullptr, lin_b, nullptr, nullptr, 1);
  // dense 2 + fused readout: relu(xtb@W+b)·wp -> atomicAdd out[batch]
  k_gemm<<<gemm_grid, 256, 0, stream>>>(
      xtb, nullptr, Wt + (size_t)4*16384, nullptr,
      wp_W, nullptr, nullptr, nullptr, lin_b + H, batch, out, 2);
}